// Round 4
// baseline (141.805 us; speedup 1.0000x reference)
//
#include <hip/hip_runtime.h>

// ---------------------------------------------------------------------------
// Attention_25254407701324: full MHA forward on MI355X (gfx950).
// B=2, N=2048, E=1024, H=16, D=64.  bf16 MFMA, fp32 accum.
// Flash: swapped-QK^T 32x32x16, key-split wave pairs, 4-wave blocks (grid
// 1024 = 4 blocks/CU), in-register softmax, l via ones-MFMA, permlane repack.
// GEMMs: compile-time MODE specialization (runtime branch in K-loop was a
// 14us regression in R3).
// ---------------------------------------------------------------------------

typedef __bf16 bf16x8 __attribute__((ext_vector_type(8)));
typedef float  f32x4  __attribute__((ext_vector_type(4)));
typedef float  f32x16 __attribute__((ext_vector_type(16)));
using u16 = unsigned short;
using u32 = unsigned int;
typedef u16 u16x8 __attribute__((ext_vector_type(8)));
typedef u16 u16x4 __attribute__((ext_vector_type(4)));
typedef u32 u32x4 __attribute__((ext_vector_type(4)));

constexpr int BATCH = 2, SEQ = 2048, EMB = 1024, NH = 16, HD = 64;
constexpr int MTOT = BATCH * SEQ;      // 4096
constexpr int KTOT = EMB;              // 1024
constexpr int NTOT = EMB;              // 1024
constexpr float LOG2E = 1.44269504088896340736f;

// ws layout (bytes)
constexpr size_t OFF_XBF = 0;                         // 8 MB (reused as O)
constexpr size_t OFF_WQ  = 8u * 1024 * 1024;
constexpr size_t OFF_WK  = OFF_WQ + 2u * 1024 * 1024;
constexpr size_t OFF_WV  = OFF_WK + 2u * 1024 * 1024;
constexpr size_t OFF_WO  = OFF_WV + 2u * 1024 * 1024;
constexpr size_t OFF_Q   = OFF_WO + 2u * 1024 * 1024; // 16 MB
constexpr size_t OFF_K   = OFF_Q  + 8u * 1024 * 1024;
constexpr size_t OFF_VT  = OFF_K  + 8u * 1024 * 1024; // ends at 40 MB

__device__ __forceinline__ u16 f2bf(float f) {
  u32 u = __builtin_bit_cast(u32, f);
  u = (u + 0x7fffu + ((u >> 16) & 1u)) >> 16;   // RNE
  return (u16)u;
}

__device__ __forceinline__ bf16x8 ld_bf16x8(const u16* p) {
  return __builtin_bit_cast(bf16x8, *(const u16x8*)p);
}

__device__ __forceinline__ float fexp2(float x) {
#if __has_builtin(__builtin_amdgcn_exp2f)
  return __builtin_amdgcn_exp2f(x);
#else
  return exp2f(x);
#endif
}

__device__ __forceinline__ float fmax3(float a, float b, float c) {
  float d;
  asm("v_max3_f32 %0, %1, %2, %3" : "=v"(d) : "v"(a), "v"(b), "v"(c));
  return d;
}

// packed f32x2 -> bf16x2 (RNE), low word = first arg
__device__ __forceinline__ u32 cvtpk(float lo, float hi_) {
  u32 r;
  asm("v_cvt_pk_bf16_f32 %0, %1, %2" : "=v"(r) : "v"(lo), "v"(hi_));
  return r;
}

// async global->LDS, 16B per lane. LDS dest = wave-uniform base + lane*16.
__device__ __forceinline__ void stage16(const void* g, void* l) {
#if __has_builtin(__builtin_amdgcn_global_load_lds)
  __builtin_amdgcn_global_load_lds(
      (__attribute__((address_space(1))) void*)const_cast<void*>(g),
      (__attribute__((address_space(3))) void*)l, 16, 0, 0);
#else
  int lane = threadIdx.x & 63;
  uint4 v = *(const uint4*)g;
  *(uint4*)((char*)l + lane * 16) = v;
#endif
}

// ---------------------------------------------------------------------------
// fp32 -> bf16 for x and the 4 weight matrices in one launch (z = 0..4)
__global__ __launch_bounds__(256) void cvt_all(
    const float* __restrict__ x, const float* __restrict__ wq,
    const float* __restrict__ wk, const float* __restrict__ wv,
    const float* __restrict__ wo, u16* __restrict__ ox, u16* __restrict__ oq,
    u16* __restrict__ okk, u16* __restrict__ ov, u16* __restrict__ oo) {
  int z = blockIdx.z;
  const float* in = (z == 0) ? x : (z == 1) ? wq : (z == 2) ? wk : (z == 3) ? wv : wo;
  u16* out = (z == 0) ? ox : (z == 1) ? oq : (z == 2) ? okk : (z == 3) ? ov : oo;
  int n4 = (z == 0) ? (MTOT * EMB / 4) : (EMB * EMB / 4);
  int i = blockIdx.x * blockDim.x + threadIdx.x;
  if (i >= n4) return;
  float4 f = ((const float4*)in)[i];
  u32 lo = (u32)f2bf(f.x) | ((u32)f2bf(f.y) << 16);
  u32 hi = (u32)f2bf(f.z) | ((u32)f2bf(f.w) << 16);
  ((uint2*)out)[i] = make_uint2(lo, hi);
}

// ---------------------------------------------------------------------------
// C = A[M][K] * B^T + bias, Bm is [N][K].  Compile-time MODE:
// 0: bf16 scatter -> [B][H][N][D] (Q,K; oscale applied before cvt)
// 1: bf16 -> [B][H][D][N] (V^T) via swapped-operand mfma (C^T layout ->
//    lanes run along tokens -> coalesced stores)
// 2: fp32 row-major [M][N] -> out
template <int MODE>
__device__ __forceinline__ void gemm_bt_core(const u16* __restrict__ A,
                                             const u16* __restrict__ Bm,
                                             const float* __restrict__ bias,
                                             void* __restrict__ out,
                                             float oscale) {
  __shared__ __align__(16) u16 sA[128 * 32];
  __shared__ __align__(16) u16 sB[128 * 32];
  const int tid = threadIdx.x, w = tid >> 6, ln = tid & 63;
  const int wr = w >> 1, wc = w & 1, qq = ln >> 4, t = ln & 15;
  const int m0 = blockIdx.y * 128, n0 = blockIdx.x * 128;

  f32x4 acc[4][4] = {};

  for (int kt = 0; kt < KTOT; kt += 32) {
#pragma unroll
    for (int j = 0; j < 2; j++) {
      int ck = w * 128 + j * 64 + ln;
      int r = ck >> 2, c2 = ck & 3;
      stage16(&A[(size_t)(m0 + r) * KTOT + kt + c2 * 8], &sA[(w * 128 + j * 64) * 8]);
      stage16(&Bm[(size_t)(n0 + r) * KTOT + kt + c2 * 8], &sB[(w * 128 + j * 64) * 8]);
    }
    __syncthreads();

    bf16x8 av[4], bv[4];
#pragma unroll
    for (int f = 0; f < 4; f++) {
      av[f] = ld_bf16x8(&sA[(wr * 64 + f * 16 + t) * 32 + qq * 8]);
      bv[f] = ld_bf16x8(&sB[(wc * 64 + f * 16 + t) * 32 + qq * 8]);
    }
#pragma unroll
    for (int i = 0; i < 4; i++)
#pragma unroll
      for (int j = 0; j < 4; j++) {
        if (MODE == 1)
          acc[i][j] = __builtin_amdgcn_mfma_f32_16x16x32_bf16(bv[j], av[i], acc[i][j], 0, 0, 0);
        else
          acc[i][j] = __builtin_amdgcn_mfma_f32_16x16x32_bf16(av[i], bv[j], acc[i][j], 0, 0, 0);
      }
    __syncthreads();
  }

  if (MODE == 1) {
    // acc[i][j] = C^T block: row = n (d), col = t -> token. Coalesced stores.
#pragma unroll
    for (int j = 0; j < 4; j++)
#pragma unroll
      for (int ii = 0; ii < 4; ii++) {
        int n = n0 + wc * 64 + j * 16 + qq * 4 + ii;
        float bn = bias[n];
        int h = n >> 6, d = n & 63;
#pragma unroll
        for (int i = 0; i < 4; i++) {
          int mm = m0 + wr * 64 + i * 16 + t;
          int b = mm >> 11, tok = mm & 2047;
          ((u16*)out)[(((size_t)(b * NH + h)) * HD + d) * SEQ + tok] =
              f2bf(acc[i][j][ii] + bn);
        }
      }
    return;
  }

#pragma unroll
  for (int fc = 0; fc < 4; fc++) {
    int n = n0 + wc * 64 + fc * 16 + t;
    float bn = bias[n];
#pragma unroll
    for (int fr = 0; fr < 4; fr++) {
#pragma unroll
      for (int i = 0; i < 4; i++) {
        int m = m0 + wr * 64 + fr * 16 + qq * 4 + i;
        float v = (acc[fr][fc][i] + bn) * oscale;
        if (MODE == 2) {
          ((float*)out)[(size_t)m * NTOT + n] = v;
        } else {
          int b = m >> 11, tok = m & 2047, h = n >> 6, d = n & 63;
          ((u16*)out)[(((size_t)(b * NH + h)) * SEQ + tok) * HD + d] = f2bf(v);
        }
      }
    }
  }
}

__global__ __launch_bounds__(256) void gemm_qk(
    const u16* __restrict__ A, const u16* __restrict__ WQ, const u16* __restrict__ WK,
    const float* __restrict__ bq, const float* __restrict__ bk, u16* Qo, u16* Ko) {
  if (blockIdx.z == 0)
    gemm_bt_core<0>(A, WQ, bq, Qo, LOG2E);   // Q pre-scaled: softmax in base-2
  else
    gemm_bt_core<0>(A, WK, bk, Ko, 1.0f);
}

__global__ __launch_bounds__(256) void gemm_vt(const u16* __restrict__ A,
                                               const u16* __restrict__ WV,
                                               const float* __restrict__ bv,
                                               u16* Vo) {
  gemm_bt_core<1>(A, WV, bv, Vo, 1.0f);
}

__global__ __launch_bounds__(256) void gemm_o(const u16* __restrict__ A,
                                              const u16* __restrict__ WO,
                                              const float* __restrict__ bo,
                                              float* __restrict__ out) {
  gemm_bt_core<2>(A, WO, bo, out, 1.0f);
}

// ---------------------------------------------------------------------------
// Flash attention, swapped-QK^T 32x32x16, key-split wave pairs.
// Block = 4 waves (256 thr): (w&1) = q-split (2 x 32 rows), (w>>1) = key half.
// Grid = 32 bh x 32 q-tiles = 1024 blocks -> exactly 4 blocks/CU (LDS 34KB).
// Pair (w, w^2) merges m/l/O at the end through LDS (fp32).
__global__ __launch_bounds__(256, 4) void flash_attn(const u16* __restrict__ Q,
                                                     const u16* __restrict__ Kg,
                                                     const u16* __restrict__ VT,
                                                     u16* __restrict__ O) {
  // XCD-chunked decode: each XCD owns 4 bh (2MB K/V -> L2-resident).
  const int e = blockIdx.x;            // 0..1023
  const int xcd = e & 7, slot = e >> 3;
  const int bh = xcd * 4 + (slot & 3);
  const int qt = slot >> 2;            // 0..31

  const int tid = threadIdx.x, w = tid >> 6, ln = tid & 63;
  const int c = ln & 31, hi = ln >> 5;
  const int kb = w >> 1;               // key half of the pair
  const int q0 = qt * 64 + (w & 1) * 32;

  const u16* Qb = Q + (size_t)bh * SEQ * HD;
  const u16* Kb = Kg + (size_t)bh * SEQ * HD;
  const u16* Vb = VT + (size_t)bh * HD * SEQ;

  __shared__ __align__(16) u16 sK[2][64 * 64];
  __shared__ __align__(16) u16 sV[2][64 * 64];
  __shared__ float2 sml[4][64];

  // Q B-frags (hoisted): qf[ks] elem j = Q[q0+c][ks*16 + hi*8 + j]
  bf16x8 qf[4];
#pragma unroll
  for (int ks = 0; ks < 4; ks++)
    qf[ks] = ld_bf16x8(&Qb[(size_t)(q0 + c) * HD + ks * 16 + hi * 8]);

  const bf16x8 ones = __builtin_bit_cast(
      bf16x8, (u16x8){0x3f80, 0x3f80, 0x3f80, 0x3f80, 0x3f80, 0x3f80, 0x3f80, 0x3f80});

  f32x16 ot[2];
  ot[0] = 0.f; ot[1] = 0.f;
  f32x16 acc_l = 0.f;                  // only [0] meaningful
  float m = -1e30f;

  // stage K tile [64 key][64 d] and V^T tile [64 d][64 key]; 4 waves cover
  // both (2 chunks each); 16B-chunk XOR-swizzle on the GLOBAL source.
#define STAGE(buf, kt)                                                         \
  {                                                                            \
    _Pragma("unroll") for (int j = 0; j < 2; j++) {                            \
      int ck = w * 128 + j * 64 + ln;                                          \
      int r = ck >> 3, c2 = ck & 7, c2s = c2 ^ (r & 7);                        \
      stage16(&Kb[(size_t)((kt) + r) * HD + c2s * 8],                          \
              &sK[buf][(size_t)(w * 128 + j * 64) * 8]);                       \
      stage16(&Vb[(size_t)r * SEQ + (kt) + c2s * 8],                           \
              &sV[buf][(size_t)(w * 128 + j * 64) * 8]);                       \
    }                                                                          \
  }

  STAGE(0, 0)
  __syncthreads();

  int it = 0;
  for (int kt = 0; kt < SEQ; kt += 64, it ^= 1) {
    if (kt + 64 < SEQ) STAGE(it ^ 1, kt + 64)
    const u16* kbuf = sK[it];
    const u16* vbuf = sV[it];

    // ---- S^T = K . Q^T for this wave's 32 keys (4 mfma over d) ----
    f32x16 st = 0.f;
    __builtin_amdgcn_s_setprio(1);
#pragma unroll
    for (int ks = 0; ks < 4; ks++) {
      int row = kb * 32 + c;
      int boff = ((2 * ks + hi) ^ (row & 7)) << 4;
      bf16x8 kf = ld_bf16x8((const u16*)((const char*)(kbuf + row * 64) + boff));
      st = __builtin_amdgcn_mfma_f32_32x32x16_bf16(kf, qf[ks], st, 0, 0, 0);
    }
    __builtin_amdgcn_s_setprio(0);

    // ---- online softmax (base 2), q = lane&31; max via v_max3 ----
    float a0 = fmax3(st[0], st[1], st[2]);
    float a1 = fmax3(st[3], st[4], st[5]);
    float a2 = fmax3(st[6], st[7], st[8]);
    float a3 = fmax3(st[9], st[10], st[11]);
    float a4 = fmax3(st[12], st[13], st[14]);
    float a5 = fmaxf(st[15], a0);
    float b0 = fmax3(a1, a2, a3);
    float b1 = fmax3(a4, a5, b0);
    float pmax = fmaxf(b1, __shfl_xor(b1, 32));

    if (!__all(pmax <= m + 8.0f)) {       // defer-max (THR=8, base-2 units)
      float mn = fmaxf(m, pmax);
      float sc = fexp2(m - mn);
      acc_l[0] *= sc;
#pragma unroll
      for (int i = 0; i < 16; i++) { ot[0][i] *= sc; ot[1][i] *= sc; }
      m = mn;
    }

#pragma unroll
    for (int i = 0; i < 16; i++) st[i] = fexp2(st[i] - m);

    // ---- repack P (S^T C-layout) -> PV B-frags via permlane32_swap ----
    // pb[ks2] elem j on half h: key = kb*32 + ks2*16 + h*8 + j
    bf16x8 pb[2];
#pragma unroll
    for (int ks2 = 0; ks2 < 2; ks2++) {
      const int R0 = 8 * ks2;                    // reg base, consumer half 0
      const int R1 = 4 * ((2 * ks2 + 1) & 3);    // reg base, consumer half 1
      u32 X0 = cvtpk(st[R0], st[R0 + 1]);
      u32 X1 = cvtpk(st[R0 + 2], st[R0 + 3]);
      u32 Y0 = cvtpk(st[R1], st[R1 + 1]);
      u32 Y1 = cvtpk(st[R1 + 2], st[R1 + 3]);
      asm("v_permlane32_swap_b32 %0, %1" : "+v"(X0), "+v"(Y0));
      asm("v_permlane32_swap_b32 %0, %1" : "+v"(X1), "+v"(Y1));
      u32x4 wd; wd.x = X0; wd.y = X1; wd.z = Y0; wd.w = Y1;
      pb[ks2] = __builtin_bit_cast(bf16x8, wd);
    }

    // ---- O^T += V^T . P^T ; l via ones-row MFMA ----
    __builtin_amdgcn_s_setprio(1);
#pragma unroll
    for (int ks2 = 0; ks2 < 2; ks2++) {
#pragma unroll
      for (int db = 0; db < 2; db++) {
        int row = db * 32 + c;
        int boff = ((kb * 4 + ks2 * 2 + hi) ^ (row & 7)) << 4;
        bf16x8 vf = ld_bf16x8((const u16*)((const char*)(vbuf + row * 64) + boff));
        ot[db] = __builtin_amdgcn_mfma_f32_32x32x16_bf16(vf, pb[ks2], ot[db], 0, 0, 0);
      }
      acc_l = __builtin_amdgcn_mfma_f32_32x32x16_bf16(ones, pb[ks2], acc_l, 0, 0, 0);
    }
    __builtin_amdgcn_s_setprio(0);
    __syncthreads();
  }
#undef STAGE

  // ---- pair merge (w <-> w^2) through LDS, then store ----
  float myl = acc_l[0];
  const int pair = w & 1;
  float* xA = (float*)sK;   // key-half-0 waves deposit their ot[1] here
  float* xB = (float*)sV;   // key-half-1 waves deposit their ot[0] here
  {
    f32x16 give = (kb == 0) ? ot[1] : ot[0];
    *(f32x16*)((kb == 0 ? xA : xB) + (size_t)(pair * 64 + ln) * 16) = give;
    sml[w][ln] = make_float2(m, myl);
  }
  __syncthreads();

  float2 po = sml[w ^ 2][ln];
  float M2 = fmaxf(m, po.x);
  float s_me = fexp2(m - M2), s_po = fexp2(po.x - M2);
  float lf = myl * s_me + po.y * s_po;
  float inv = 1.0f / (lf * 32.0f);
  f32x16 oth = *(const f32x16*)((kb == 0 ? xB : xA) + (size_t)(pair * 64 + ln) * 16);
  f32x16 own = (kb == 0) ? ot[0] : ot[1];
  const int db = kb;

  const int b = bh >> 4, h = bh & 15;
  u16* obase = O + ((size_t)(b * SEQ + q0 + c)) * EMB + h * HD;
#pragma unroll
  for (int g = 0; g < 4; g++) {
    u16x4 pkt;
#pragma unroll
    for (int i = 0; i < 4; i++)
      pkt[i] = f2bf((own[g * 4 + i] * s_me + oth[g * 4 + i] * s_po) * inv);
    *(u16x4*)(obase + db * 32 + g * 8 + hi * 4) = pkt;
  }
}

// ---------------------------------------------------------------------------
extern "C" void kernel_launch(void* const* d_in, const int* in_sizes, int n_in,
                              void* d_out, int out_size, void* d_ws, size_t ws_size,
                              hipStream_t stream) {
  const float* x  = (const float*)d_in[0];
  const float* Wq = (const float*)d_in[1];
  const float* bq = (const float*)d_in[2];
  const float* Wk = (const float*)d_in[3];
  const float* bk = (const float*)d_in[4];
  const float* Wv = (const float*)d_in[5];
  const float* bv = (const float*)d_in[6];
  const float* Wo = (const float*)d_in[7];
  const float* bo = (const float*)d_in[8];

  char* ws = (char*)d_ws;
  u16* xbf = (u16*)(ws + OFF_XBF);   // x bf16; later reused as O
  u16* wqb = (u16*)(ws + OFF_WQ);
  u16* wkb = (u16*)(ws + OFF_WK);
  u16* wvb = (u16*)(ws + OFF_WV);
  u16* wob = (u16*)(ws + OFF_WO);
  u16* Qw  = (u16*)(ws + OFF_Q);
  u16* Kw  = (u16*)(ws + OFF_K);
  u16* Vw  = (u16*)(ws + OFF_VT);

  // 1) fp32 -> bf16 (x + 4 weights, one launch)
  cvt_all<<<dim3(MTOT * EMB / 4 / 256, 1, 5), 256, 0, stream>>>(
      x, Wq, Wk, Wv, Wo, xbf, wqb, wkb, wvb, wob);

  // 2) projections
  gemm_qk<<<dim3(NTOT / 128, MTOT / 128, 2), 256, 0, stream>>>(
      xbf, wqb, wkb, bq, bk, Qw, Kw);
  gemm_vt<<<dim3(NTOT / 128, MTOT / 128), 256, 0, stream>>>(xbf, wvb, bv, Vw);

  // 3) flash attention -> O (reuses xbf region)
  flash_attn<<<dim3(1024), 256, 0, stream>>>(Qw, Kw, Vw, xbf);

  // 4) output projection -> d_out (fp32)
  gemm_o<<<dim3(NTOT / 128, MTOT / 128), 256, 0, stream>>>(xbf, wob, bo, (float*)d_out);
}

// Round 5
// 134.980 us; speedup vs baseline: 1.0506x; 1.0506x over previous
//
#include <hip/hip_runtime.h>

// ---------------------------------------------------------------------------
// Attention_25254407701324: full MHA forward on MI355X (gfx950).
// B=2, N=2048, E=1024, H=16, D=64.  bf16 MFMA, fp32 accum.
// Flash: R3 structure (8-wave/512-thr blocks, key-split wave pairs, grid 512).
// GEMMs: ONE qkv launch (768 blocks) with top-level branch into compile-time
// specialized cores (R4 lesson: splitting launches costs ~15us in tails).
// ---------------------------------------------------------------------------

typedef __bf16 bf16x8 __attribute__((ext_vector_type(8)));
typedef float  f32x4  __attribute__((ext_vector_type(4)));
typedef float  f32x16 __attribute__((ext_vector_type(16)));
using u16 = unsigned short;
using u32 = unsigned int;
typedef u16 u16x8 __attribute__((ext_vector_type(8)));
typedef u16 u16x4 __attribute__((ext_vector_type(4)));
typedef u32 u32x4 __attribute__((ext_vector_type(4)));

constexpr int BATCH = 2, SEQ = 2048, EMB = 1024, NH = 16, HD = 64;
constexpr int MTOT = BATCH * SEQ;      // 4096
constexpr int KTOT = EMB;              // 1024
constexpr int NTOT = EMB;              // 1024
constexpr float LOG2E = 1.44269504088896340736f;

// ws layout (bytes)
constexpr size_t OFF_XBF = 0;                         // 8 MB (reused as O)
constexpr size_t OFF_WQ  = 8u * 1024 * 1024;
constexpr size_t OFF_WK  = OFF_WQ + 2u * 1024 * 1024;
constexpr size_t OFF_WV  = OFF_WK + 2u * 1024 * 1024;
constexpr size_t OFF_WO  = OFF_WV + 2u * 1024 * 1024;
constexpr size_t OFF_Q   = OFF_WO + 2u * 1024 * 1024; // 16 MB
constexpr size_t OFF_K   = OFF_Q  + 8u * 1024 * 1024;
constexpr size_t OFF_VT  = OFF_K  + 8u * 1024 * 1024; // ends at 40 MB

__device__ __forceinline__ u16 f2bf(float f) {
  u32 u = __builtin_bit_cast(u32, f);
  u = (u + 0x7fffu + ((u >> 16) & 1u)) >> 16;   // RNE
  return (u16)u;
}

__device__ __forceinline__ bf16x8 ld_bf16x8(const u16* p) {
  return __builtin_bit_cast(bf16x8, *(const u16x8*)p);
}

__device__ __forceinline__ float fexp2(float x) {
#if __has_builtin(__builtin_amdgcn_exp2f)
  return __builtin_amdgcn_exp2f(x);
#else
  return exp2f(x);
#endif
}

__device__ __forceinline__ float fmax3(float a, float b, float c) {
  float d;
  asm("v_max3_f32 %0, %1, %2, %3" : "=v"(d) : "v"(a), "v"(b), "v"(c));
  return d;
}

// packed f32x2 -> bf16x2 (RNE), low word = first arg
__device__ __forceinline__ u32 cvtpk(float lo, float hi_) {
  u32 r;
  asm("v_cvt_pk_bf16_f32 %0, %1, %2" : "=v"(r) : "v"(lo), "v"(hi_));
  return r;
}

// async global->LDS, 16B per lane. LDS dest = wave-uniform base + lane*16.
__device__ __forceinline__ void stage16(const void* g, void* l) {
#if __has_builtin(__builtin_amdgcn_global_load_lds)
  __builtin_amdgcn_global_load_lds(
      (__attribute__((address_space(1))) void*)const_cast<void*>(g),
      (__attribute__((address_space(3))) void*)l, 16, 0, 0);
#else
  int lane = threadIdx.x & 63;
  uint4 v = *(const uint4*)g;
  *(uint4*)((char*)l + lane * 16) = v;
#endif
}

// ---------------------------------------------------------------------------
// fp32 -> bf16 for x and the 4 weight matrices in one launch (z = 0..4)
__global__ __launch_bounds__(256) void cvt_all(
    const float* __restrict__ x, const float* __restrict__ wq,
    const float* __restrict__ wk, const float* __restrict__ wv,
    const float* __restrict__ wo, u16* __restrict__ ox, u16* __restrict__ oq,
    u16* __restrict__ okk, u16* __restrict__ ov, u16* __restrict__ oo) {
  int z = blockIdx.z;
  const float* in = (z == 0) ? x : (z == 1) ? wq : (z == 2) ? wk : (z == 3) ? wv : wo;
  u16* out = (z == 0) ? ox : (z == 1) ? oq : (z == 2) ? okk : (z == 3) ? ov : oo;
  int n4 = (z == 0) ? (MTOT * EMB / 4) : (EMB * EMB / 4);
  int i = blockIdx.x * blockDim.x + threadIdx.x;
  if (i >= n4) return;
  float4 f = ((const float4*)in)[i];
  u32 lo = (u32)f2bf(f.x) | ((u32)f2bf(f.y) << 16);
  u32 hi = (u32)f2bf(f.z) | ((u32)f2bf(f.w) << 16);
  ((uint2*)out)[i] = make_uint2(lo, hi);
}

// ---------------------------------------------------------------------------
// C = A[M][K] * B^T + bias, Bm is [N][K].  Compile-time MODE:
// 0: bf16 scatter -> [B][H][N][D] (Q,K; oscale applied before cvt)
// 1: bf16 -> [B][H][D][N] (V^T) via swapped-operand mfma (C^T layout ->
//    lanes run along tokens -> coalesced stores)
// 2: fp32 row-major [M][N] -> out
template <int MODE>
__device__ __forceinline__ void gemm_bt_core(const u16* __restrict__ A,
                                             const u16* __restrict__ Bm,
                                             const float* __restrict__ bias,
                                             void* __restrict__ out,
                                             float oscale) {
  __shared__ __align__(16) u16 sA[128 * 32];
  __shared__ __align__(16) u16 sB[128 * 32];
  const int tid = threadIdx.x, w = tid >> 6, ln = tid & 63;
  const int wr = w >> 1, wc = w & 1, qq = ln >> 4, t = ln & 15;
  const int m0 = blockIdx.y * 128, n0 = blockIdx.x * 128;

  f32x4 acc[4][4] = {};

  for (int kt = 0; kt < KTOT; kt += 32) {
#pragma unroll
    for (int j = 0; j < 2; j++) {
      int ck = w * 128 + j * 64 + ln;
      int r = ck >> 2, c2 = ck & 3;
      stage16(&A[(size_t)(m0 + r) * KTOT + kt + c2 * 8], &sA[(w * 128 + j * 64) * 8]);
      stage16(&Bm[(size_t)(n0 + r) * KTOT + kt + c2 * 8], &sB[(w * 128 + j * 64) * 8]);
    }
    __syncthreads();

    bf16x8 av[4], bv[4];
#pragma unroll
    for (int f = 0; f < 4; f++) {
      av[f] = ld_bf16x8(&sA[(wr * 64 + f * 16 + t) * 32 + qq * 8]);
      bv[f] = ld_bf16x8(&sB[(wc * 64 + f * 16 + t) * 32 + qq * 8]);
    }
#pragma unroll
    for (int i = 0; i < 4; i++)
#pragma unroll
      for (int j = 0; j < 4; j++) {
        if (MODE == 1)
          acc[i][j] = __builtin_amdgcn_mfma_f32_16x16x32_bf16(bv[j], av[i], acc[i][j], 0, 0, 0);
        else
          acc[i][j] = __builtin_amdgcn_mfma_f32_16x16x32_bf16(av[i], bv[j], acc[i][j], 0, 0, 0);
      }
    __syncthreads();
  }

  if (MODE == 1) {
    // acc[i][j] = C^T block: row = n (d), col = t -> token. Coalesced stores.
#pragma unroll
    for (int j = 0; j < 4; j++)
#pragma unroll
      for (int ii = 0; ii < 4; ii++) {
        int n = n0 + wc * 64 + j * 16 + qq * 4 + ii;
        float bn = bias[n];
        int h = n >> 6, d = n & 63;
#pragma unroll
        for (int i = 0; i < 4; i++) {
          int mm = m0 + wr * 64 + i * 16 + t;
          int b = mm >> 11, tok = mm & 2047;
          ((u16*)out)[(((size_t)(b * NH + h)) * HD + d) * SEQ + tok] =
              f2bf(acc[i][j][ii] + bn);
        }
      }
    return;
  }

#pragma unroll
  for (int fc = 0; fc < 4; fc++) {
    int n = n0 + wc * 64 + fc * 16 + t;
    float bn = bias[n];
#pragma unroll
    for (int fr = 0; fr < 4; fr++) {
#pragma unroll
      for (int i = 0; i < 4; i++) {
        int m = m0 + wr * 64 + fr * 16 + qq * 4 + i;
        float v = (acc[fr][fc][i] + bn) * oscale;
        if (MODE == 2) {
          ((float*)out)[(size_t)m * NTOT + n] = v;
        } else {
          int b = m >> 11, tok = m & 2047, h = n >> 6, d = n & 63;
          ((u16*)out)[(((size_t)(b * NH + h)) * SEQ + tok) * HD + d] = f2bf(v);
        }
      }
    }
  }
}

// One launch, 3 z-slices -> 768 blocks (~3/CU).  Top-level branch only;
// each core instantiation has a compile-time-specialized K-loop.
__global__ __launch_bounds__(256) void gemm_qkv(
    const u16* __restrict__ A, const u16* __restrict__ WQ, const u16* __restrict__ WK,
    const u16* __restrict__ WV, const float* __restrict__ bq, const float* __restrict__ bk,
    const float* __restrict__ bv, u16* Qo, u16* Ko, u16* Vo) {
  int z = blockIdx.z;
  if (z == 2) {
    gemm_bt_core<1>(A, WV, bv, Vo, 1.0f);
  } else {
    // Q pre-scaled by log2(e) so flash softmax runs in base-2.
    gemm_bt_core<0>(A, z ? WK : WQ, z ? bk : bq, z ? Ko : Qo, z ? 1.0f : LOG2E);
  }
}

__global__ __launch_bounds__(256) void gemm_o(const u16* __restrict__ A,
                                              const u16* __restrict__ WO,
                                              const float* __restrict__ bo,
                                              float* __restrict__ out) {
  gemm_bt_core<2>(A, WO, bo, out, 1.0f);
}

// ---------------------------------------------------------------------------
// Flash attention, swapped-QK^T 32x32x16, key-split wave pairs (R3 structure).
// Block = 8 waves (512 thr): waves 0-3 = q-blocks 0-3 x keys[0:32) of each
// tile; waves 4-7 = same q-blocks x keys[32:64). Pair (w, w^4) merges m/l/O
// at the end through LDS (fp32). l accumulated via ones-row MFMA.
__global__ __launch_bounds__(512, 4) void flash_attn(const u16* __restrict__ Q,
                                                     const u16* __restrict__ Kg,
                                                     const u16* __restrict__ VT,
                                                     u16* __restrict__ O) {
  // XCD-chunked decode: each XCD owns 4 bh (2MB K/V -> L2-resident).
  const int e = blockIdx.x;            // 0..511
  const int xcd = e & 7, slot = e >> 3;
  const int bh = xcd * 4 + (slot & 3);
  const int qt = slot >> 2;            // 0..15

  const int tid = threadIdx.x, w = tid >> 6, ln = tid & 63;
  const int c = ln & 31, hi = ln >> 5;
  const int kb = w >> 2;               // key half of the pair
  const int q0 = qt * 128 + (w & 3) * 32;

  const u16* Qb = Q + (size_t)bh * SEQ * HD;
  const u16* Kb = Kg + (size_t)bh * SEQ * HD;
  const u16* Vb = VT + (size_t)bh * HD * SEQ;

  __shared__ __align__(16) u16 sK[2][64 * 64];
  __shared__ __align__(16) u16 sV[2][64 * 64];
  __shared__ float2 sml[8][64];

  // Q B-frags (hoisted): qf[ks] elem j = Q[q0+c][ks*16 + hi*8 + j]
  bf16x8 qf[4];
#pragma unroll
  for (int ks = 0; ks < 4; ks++)
    qf[ks] = ld_bf16x8(&Qb[(size_t)(q0 + c) * HD + ks * 16 + hi * 8]);

  const bf16x8 ones = __builtin_bit_cast(
      bf16x8, (u16x8){0x3f80, 0x3f80, 0x3f80, 0x3f80, 0x3f80, 0x3f80, 0x3f80, 0x3f80});

  f32x16 ot[2];
  ot[0] = 0.f; ot[1] = 0.f;
  f32x16 acc_l = 0.f;                  // only [0] meaningful
  float m = -1e30f;

  // stage K tile [64 key][64 d] and V^T tile [64 d][64 key]; 8 waves cover
  // both (1 chunk each); 16B-chunk XOR-swizzle on the GLOBAL source.
#define STAGE(buf, kt)                                                         \
  {                                                                            \
    int ck = w * 64 + ln;                                                      \
    int r = ck >> 3, c2 = ck & 7, c2s = c2 ^ (r & 7);                          \
    stage16(&Kb[(size_t)((kt) + r) * HD + c2s * 8],                            \
            &sK[buf][(size_t)(w * 64) * 8]);                                   \
    stage16(&Vb[(size_t)r * SEQ + (kt) + c2s * 8],                             \
            &sV[buf][(size_t)(w * 64) * 8]);                                   \
  }

  STAGE(0, 0)
  __syncthreads();

  int it = 0;
  for (int kt = 0; kt < SEQ; kt += 64, it ^= 1) {
    if (kt + 64 < SEQ) STAGE(it ^ 1, kt + 64)
    const u16* kbuf = sK[it];
    const u16* vbuf = sV[it];

    // ---- S^T = K . Q^T for this wave's 32 keys (4 mfma over d) ----
    f32x16 st = 0.f;
    __builtin_amdgcn_s_setprio(1);
#pragma unroll
    for (int ks = 0; ks < 4; ks++) {
      int row = kb * 32 + c;
      int boff = ((2 * ks + hi) ^ (row & 7)) << 4;
      bf16x8 kf = ld_bf16x8((const u16*)((const char*)(kbuf + row * 64) + boff));
      st = __builtin_amdgcn_mfma_f32_32x32x16_bf16(kf, qf[ks], st, 0, 0, 0);
    }
    __builtin_amdgcn_s_setprio(0);

    // ---- online softmax (base 2), q = lane&31; max via v_max3 ----
    float a0 = fmax3(st[0], st[1], st[2]);
    float a1 = fmax3(st[3], st[4], st[5]);
    float a2 = fmax3(st[6], st[7], st[8]);
    float a3 = fmax3(st[9], st[10], st[11]);
    float a4 = fmax3(st[12], st[13], st[14]);
    float a5 = fmaxf(st[15], a0);
    float b0 = fmax3(a1, a2, a3);
    float b1 = fmax3(a4, a5, b0);
    float pmax = fmaxf(b1, __shfl_xor(b1, 32));

    if (!__all(pmax <= m + 8.0f)) {       // defer-max (THR=8, base-2 units)
      float mn = fmaxf(m, pmax);
      float sc = fexp2(m - mn);
      acc_l[0] *= sc;
#pragma unroll
      for (int i = 0; i < 16; i++) { ot[0][i] *= sc; ot[1][i] *= sc; }
      m = mn;
    }

#pragma unroll
    for (int i = 0; i < 16; i++) st[i] = fexp2(st[i] - m);

    // ---- repack P (S^T C-layout) -> PV B-frags via permlane32_swap ----
    // pb[ks2] elem j on half h: key = kb*32 + ks2*16 + h*8 + j
    bf16x8 pb[2];
#pragma unroll
    for (int ks2 = 0; ks2 < 2; ks2++) {
      const int R0 = 8 * ks2;                    // reg base, consumer half 0
      const int R1 = 4 * ((2 * ks2 + 1) & 3);    // reg base, consumer half 1
      u32 X0 = cvtpk(st[R0], st[R0 + 1]);
      u32 X1 = cvtpk(st[R0 + 2], st[R0 + 3]);
      u32 Y0 = cvtpk(st[R1], st[R1 + 1]);
      u32 Y1 = cvtpk(st[R1 + 2], st[R1 + 3]);
      asm("v_permlane32_swap_b32 %0, %1" : "+v"(X0), "+v"(Y0));
      asm("v_permlane32_swap_b32 %0, %1" : "+v"(X1), "+v"(Y1));
      u32x4 wd; wd.x = X0; wd.y = X1; wd.z = Y0; wd.w = Y1;
      pb[ks2] = __builtin_bit_cast(bf16x8, wd);
    }

    // ---- O^T += V^T . P^T ; l via ones-row MFMA ----
    __builtin_amdgcn_s_setprio(1);
#pragma unroll
    for (int ks2 = 0; ks2 < 2; ks2++) {
#pragma unroll
      for (int db = 0; db < 2; db++) {
        int row = db * 32 + c;
        int boff = ((kb * 4 + ks2 * 2 + hi) ^ (row & 7)) << 4;
        bf16x8 vf = ld_bf16x8((const u16*)((const char*)(vbuf + row * 64) + boff));
        ot[db] = __builtin_amdgcn_mfma_f32_32x32x16_bf16(vf, pb[ks2], ot[db], 0, 0, 0);
      }
      acc_l = __builtin_amdgcn_mfma_f32_32x32x16_bf16(ones, pb[ks2], acc_l, 0, 0, 0);
    }
    __builtin_amdgcn_s_setprio(0);
    __syncthreads();
  }
#undef STAGE

  // ---- pair merge (w <-> w^4) through LDS, then store ----
  float myl = acc_l[0];
  const int pair = w & 3;
  float* xA = (float*)sK;   // waves 0-3 deposit their ot[1] here
  float* xB = (float*)sV;   // waves 4-7 deposit their ot[0] here
  {
    f32x16 give = (w < 4) ? ot[1] : ot[0];
    *(f32x16*)((w < 4 ? xA : xB) + (size_t)(pair * 64 + ln) * 16) = give;
    sml[w][ln] = make_float2(m, myl);
  }
  __syncthreads();

  float2 po = sml[w ^ 4][ln];
  float M2 = fmaxf(m, po.x);
  float s_me = fexp2(m - M2), s_po = fexp2(po.x - M2);
  float lf = myl * s_me + po.y * s_po;
  float inv = 1.0f / (lf * 32.0f);
  f32x16 oth = *(const f32x16*)((w < 4 ? xB : xA) + (size_t)(pair * 64 + ln) * 16);
  f32x16 own = (w < 4) ? ot[0] : ot[1];
  const int db = (w < 4) ? 0 : 1;

  const int b = bh >> 4, h = bh & 15;
  u16* obase = O + ((size_t)(b * SEQ + q0 + c)) * EMB + h * HD;
#pragma unroll
  for (int g = 0; g < 4; g++) {
    u16x4 pkt;
#pragma unroll
    for (int i = 0; i < 4; i++)
      pkt[i] = f2bf((own[g * 4 + i] * s_me + oth[g * 4 + i] * s_po) * inv);
    *(u16x4*)(obase + db * 32 + g * 8 + hi * 4) = pkt;
  }
}

// ---------------------------------------------------------------------------
extern "C" void kernel_launch(void* const* d_in, const int* in_sizes, int n_in,
                              void* d_out, int out_size, void* d_ws, size_t ws_size,
                              hipStream_t stream) {
  const float* x  = (const float*)d_in[0];
  const float* Wq = (const float*)d_in[1];
  const float* bq = (const float*)d_in[2];
  const float* Wk = (const float*)d_in[3];
  const float* bk = (const float*)d_in[4];
  const float* Wv = (const float*)d_in[5];
  const float* bv = (const float*)d_in[6];
  const float* Wo = (const float*)d_in[7];
  const float* bo = (const float*)d_in[8];

  char* ws = (char*)d_ws;
  u16* xbf = (u16*)(ws + OFF_XBF);   // x bf16; later reused as O
  u16* wqb = (u16*)(ws + OFF_WQ);
  u16* wkb = (u16*)(ws + OFF_WK);
  u16* wvb = (u16*)(ws + OFF_WV);
  u16* wob = (u16*)(ws + OFF_WO);
  u16* Qw  = (u16*)(ws + OFF_Q);
  u16* Kw  = (u16*)(ws + OFF_K);
  u16* Vw  = (u16*)(ws + OFF_VT);

  // 1) fp32 -> bf16 (x + 4 weights, one launch)
  cvt_all<<<dim3(MTOT * EMB / 4 / 256, 1, 5), 256, 0, stream>>>(
      x, Wq, Wk, Wv, Wo, xbf, wqb, wkb, wvb, wob);

  // 2) QKV projections, single launch (z: 0=Q scaled by log2e, 1=K, 2=V^T)
  gemm_qkv<<<dim3(NTOT / 128, MTOT / 128, 3), 256, 0, stream>>>(
      xbf, wqb, wkb, wvb, bq, bk, bv, Qw, Kw, Vw);

  // 3) flash attention -> O (reuses xbf region)
  flash_attn<<<dim3(512), 512, 0, stream>>>(Qw, Kw, Vw, xbf);

  // 4) output projection -> d_out (fp32)
  gemm_o<<<dim3(NTOT / 128, MTOT / 128), 256, 0, stream>>>(xbf, wob, bo, (float*)d_out);
}